// Round 3
// baseline (189.432 us; speedup 1.0000x reference)
//
#include <hip/hip_runtime.h>
#include <stdint.h>

// Bilateral filter denoiser: K=5, sigma_s=2.0, sigma_r=0.1, B=8,C=3,H=512,W=512, fp32.
// weight(dy,dx) = exp(-(n-c)^2/(2*0.1^2)) * exp(-(dx^2+dy^2)/8)
//              = exp2( RC*(n-c)^2 + L[r2] ),  r2 = (dy-2)^2+(dx-2)^2, L[r2] = -r2*log2(e)/8
// arg computed as fma(fma(RC,n,B), n, C0L), B=-2RC*c, C0L=RC*c^2 + L (2 FMAs/tap, spatial
// weight folded into the exponent constant -- 5 distinct L values hoisted per pixel).
//
// 8 px/thread (four float2 halves -> v_pk_* packed fp32), 64x32 tile, 256 threads:
// halves the wave count vs 4 px/thread (amortizes stage/barrier/epilogue) and doubles
// per-wave ILP (8 independent exp chains) to cover trans-pipe latency at low occupancy.
//
// Staging: async global->LDS via __builtin_amdgcn_global_load_lds width=16.
// Tile rows are 72 words (288B = 18x16B units) covering gx in [tileX0-4, tileX0+68):
//   - rows 16B-aligned, LDS written linearly (wave-uniform base + lane*16) as HW requires
//   - per-lane global address handles y-reflect; x is CLAMPED to [0,508] (garbage columns
//     are outside the compute window except 2 cols on x-border blocks, fixed up scalar)
//   - 648 units total = 3 gload_lds instrs/wave (64 + 64 + 34 active lanes)
// Compute window for thread = 16 words [txg*8, txg*8+16): four aligned ds_read_b128
// (Q0..Q3); pixels are words +4..+11 (Q1,Q2), taps use words +2..+13.
// Center tap: weight == 1 exactly -> ws init 1, acc init c; ws>=1 so no clip, rcp ok.

#define KK 5
#define HALO 2
#define TX 64          // tile width (pixels)
#define TY 32          // tile height
#define PXT 8          // pixels per thread along x
#define LW 72          // staged words per row: [tileX0-4, tileX0+68)
#define LH (TY + 2*HALO)   // 36 rows
#define LSTRIDE 72         // 288B rows, 16B-aligned
#define UNITS_PER_ROW 18   // 72 words / 4
#define NUNITS (LH * UNITS_PER_ROW)  // 648
#define IMG_H 512
#define IMG_W 512

typedef float v2f __attribute__((ext_vector_type(2)));
typedef float v4f __attribute__((ext_vector_type(4)));

#if defined(__has_builtin)
#if __has_builtin(__builtin_amdgcn_exp2f)
#define FAST_EXP2(x) __builtin_amdgcn_exp2f(x)
#else
#define FAST_EXP2(x) exp2f(x)
#endif
#if __has_builtin(__builtin_amdgcn_rcpf)
#define FAST_RCP(x) __builtin_amdgcn_rcpf(x)
#else
#define FAST_RCP(x) (1.0f / (x))
#endif
#if __has_builtin(__builtin_amdgcn_global_load_lds)
#define HAVE_GLOAD_LDS 1
#endif
#else
#define FAST_EXP2(x) exp2f(x)
#define FAST_RCP(x) (1.0f / (x))
#endif

__device__ __forceinline__ int reflect_idx(int i, int n) {
    i = (i < 0) ? -i : i;
    i = (i >= n) ? (2 * n - 2 - i) : i;
    return i;
}

#ifdef HAVE_GLOAD_LDS
__device__ __forceinline__ void async_copy16(const float* g, float* l) {
    // generic->AS(1) cast for global src; LDS ptr via 32-bit truncation (flat LDS
    // addresses are aperture|offset with 4GB-aligned aperture -> low 32 bits = offset).
    auto gp = (const __attribute__((address_space(1))) void*)g;
    auto lp = (__attribute__((address_space(3))) void*)(uint32_t)(uintptr_t)l;
    __builtin_amdgcn_global_load_lds(gp, lp, 16, 0, 0);
}
#endif

struct H4 { v2f a, b, c, d; };

__global__ __launch_bounds__(256, 4)
void bilateral_kernel(const float* __restrict__ x, float* __restrict__ out) {
    __shared__ alignas(16) float tile[LH * LSTRIDE];

    const int tid = threadIdx.x;
    const int tileX0 = blockIdx.x * TX;
    const int tileY0 = blockIdx.y * TY;
    const int img = blockIdx.z;
    const float* __restrict__ src = x + (size_t)img * (IMG_H * IMG_W);
    float* __restrict__ dst = out + (size_t)img * (IMG_H * IMG_W);

#ifdef HAVE_GLOAD_LDS
    // ---- async stage: 648 16B units over 4 waves (162 each = 64 + 64 + 34) ----
    {
        const int wv = tid >> 6;
        const int ln = tid & 63;
        const int u0 = wv * 162;
        #pragma unroll
        for (int k = 0; k < 3; k++) {
            if (k < 2 || ln < 34) {
                int u = u0 + k * 64 + ln;
                int r = u / UNITS_PER_ROW;
                int c = u - r * UNITS_PER_ROW;
                int gy = reflect_idx(tileY0 - HALO + r, IMG_H);
                int gxw = tileX0 - 4 + c * 4;
                gxw = max(gxw, 0); gxw = min(gxw, IMG_W - 4);
                async_copy16(src + gy * IMG_W + gxw, &tile[(u0 + k * 64) * 4]);
            }
        }
    }
    __syncthreads();   // drains vmcnt -> gload_lds data visible

    // ---- x-border fixup: clamped loads put wrong values in 2 needed halo cols ----
    {
        const bool isL = (tileX0 == 0);
        const bool isR = (tileX0 == IMG_W - TX);
        if (isL | isR) {
            if (tid < 2 * LH) {
                int r = tid >> 1, k = tid & 1;
                int gy = reflect_idx(tileY0 - HALO + r, IMG_H);
                const float* srow = src + gy * IMG_W;
                if (isL) tile[r * LSTRIDE + 2 + k] = srow[2 - k];        // gx -2,-1 -> 2,1
                else     tile[r * LSTRIDE + 68 + k] = srow[510 - k];     // gx 512,513 -> 510,509
            }
            __syncthreads();
        }
    }
#else
    // fallback: float2-vectorized manual staging
    for (int u = tid; u < LH * (LW / 2); u += 256) {
        int r = u / (LW / 2);
        int c = (u - r * (LW / 2)) * 2;
        int gy = reflect_idx(tileY0 - HALO + r, IMG_H);
        const float* srow = src + gy * IMG_W;
        int gx0 = tileX0 - 4 + c;
        float2 v;
        if (gx0 >= 0 && gx0 + 1 < IMG_W) {
            v = *reinterpret_cast<const float2*>(&srow[gx0]);
        } else {
            v.x = srow[reflect_idx(gx0, IMG_W)];
            v.y = srow[reflect_idx(gx0 + 1, IMG_W)];
        }
        *reinterpret_cast<float2*>(&tile[r * LSTRIDE + c]) = v;
    }
    __syncthreads();
#endif

    const int txg = tid & 7;       // thread x-group: 0..7
    const int ty  = tid >> 3;      // thread row:     0..31
    const int lxw = txg * PXT;     // first word of this thread's 4-quad read window

    const float RC = -72.13475204444817f;        // -1/(2*0.1^2) * log2(e)
    // L[r2] = -r2 * log2(e)/8, r2 in {1,2,4,5,8}
    const float L1 = -0.18033688011112043f;
    const float L2 = -0.36067376022224086f;
    const float L4 = -0.7213475204444817f;
    const float L5 = -0.9016844005556021f;
    const float L8 = -1.4426950408889634f;
    const v2f RCv = {RC, RC};

    // aligned b128 row reads: 16 words at (ty+dy)*72 + lxw (32B-aligned)
    auto ldrow = [&](int dy, v4f& Q0, v4f& Q1, v4f& Q2, v4f& Q3) {
        const v4f* p = reinterpret_cast<const v4f*>(&tile[(ty + dy) * LSTRIDE + lxw]);
        Q0 = p[0]; Q1 = p[1]; Q2 = p[2]; Q3 = p[3];
    };

    // center row (dy=2): pixels are words +4..+11 = Q1,Q2
    v4f Q20, Q21, Q22, Q23;
    ldrow(2, Q20, Q21, Q22, Q23);
    const v2f cA = {Q21[0], Q21[1]};
    const v2f cB = {Q21[2], Q21[3]};
    const v2f cC = {Q22[0], Q22[1]};
    const v2f cD = {Q22[2], Q22[3]};

    // per-pixel exponent-poly coefficients: arg = RC*n^2 + B*n + (C0 + L[r2])
    const H4 Bc = {cA * (-2.0f * RC), cB * (-2.0f * RC), cC * (-2.0f * RC), cD * (-2.0f * RC)};
    const v2f C0A = (cA * cA) * RC;
    const v2f C0B = (cB * cB) * RC;
    const v2f C0C = (cC * cC) * RC;
    const v2f C0D = (cD * cD) * RC;
    const H4 C1 = {C0A + L1, C0B + L1, C0C + L1, C0D + L1};
    const H4 C2 = {C0A + L2, C0B + L2, C0C + L2, C0D + L2};
    const H4 C4 = {C0A + L4, C0B + L4, C0C + L4, C0D + L4};
    const H4 C5 = {C0A + L5, C0B + L5, C0C + L5, C0D + L5};
    const H4 C8 = {C0A + L8, C0B + L8, C0C + L8, C0D + L8};

    // center tap folded in: weight exactly 1
    v2f wsA = {1.0f, 1.0f}, wsB = {1.0f, 1.0f}, wsC = {1.0f, 1.0f}, wsD = {1.0f, 1.0f};
    v2f accA = cA, accB = cB, accC = cC, accD = cD;

    auto tap = [&](v2f nA, v2f nB, v2f nC, v2f nD, const H4& C) {
        v2f tA = __builtin_elementwise_fma(__builtin_elementwise_fma(RCv, nA, Bc.a), nA, C.a);
        v2f tB = __builtin_elementwise_fma(__builtin_elementwise_fma(RCv, nB, Bc.b), nB, C.b);
        v2f tC = __builtin_elementwise_fma(__builtin_elementwise_fma(RCv, nC, Bc.c), nC, C.c);
        v2f tD = __builtin_elementwise_fma(__builtin_elementwise_fma(RCv, nD, Bc.d), nD, C.d);
        v2f eA, eB, eC, eD;
        eA.x = FAST_EXP2(tA.x); eA.y = FAST_EXP2(tA.y);
        eB.x = FAST_EXP2(tB.x); eB.y = FAST_EXP2(tB.y);
        eC.x = FAST_EXP2(tC.x); eC.y = FAST_EXP2(tC.y);
        eD.x = FAST_EXP2(tD.x); eD.y = FAST_EXP2(tD.y);
        wsA += eA; wsB += eB; wsC += eC; wsD += eD;
        accA = __builtin_elementwise_fma(eA, nA, accA);
        accB = __builtin_elementwise_fma(eB, nB, accB);
        accC = __builtin_elementwise_fma(eC, nC, accC);
        accD = __builtin_elementwise_fma(eD, nD, accD);
    };

    // window words w0..w15 (quads Q0..Q3), taps use w2..w13.
    // even pairs Ek=(w2k,w2k+1) k=1..6; odd pairs Ok=(w2k+1,w2k+2) k=1..5.
    //  dx0:(E1..E4)  dx1:(O1..O4)  dx2:(E2..E5)  dx3:(O2..O5)  dx4:(E3..E6)
    auto dorow = [&](v4f Q0, v4f Q1, v4f Q2, v4f Q3,
                     const H4& Ca, const H4& Cb, const H4& Cc, bool center_row) {
        v2f E1 = {Q0[2], Q0[3]};
        v2f E2 = {Q1[0], Q1[1]};
        v2f E3 = {Q1[2], Q1[3]};
        v2f E4 = {Q2[0], Q2[1]};
        v2f E5 = {Q2[2], Q2[3]};
        v2f E6 = {Q3[0], Q3[1]};
        v2f O1 = {Q0[3], Q1[0]};
        v2f O2 = {Q1[1], Q1[2]};
        v2f O3 = {Q1[3], Q2[0]};
        v2f O4 = {Q2[1], Q2[2]};
        v2f O5 = {Q2[3], Q3[0]};
        tap(E1, E2, E3, E4, Ca);                   // dx = 0
        tap(O1, O2, O3, O4, Cb);                   // dx = 1
        if (!center_row) tap(E2, E3, E4, E5, Cc);  // dx = 2 (non-center rows)
        tap(O2, O3, O4, O5, Cb);                   // dx = 3
        tap(E3, E4, E5, E6, Ca);                   // dx = 4
    };

    // dy = 2 first (row already loaded): r2 = {4,1,-,1,4}
    dorow(Q20, Q21, Q22, Q23, C4, C1, C1, true);

    #pragma unroll
    for (int dy = 0; dy < KK; dy++) {
        if (dy == 2) continue;
        v4f Q0, Q1, Q2, Q3;
        ldrow(dy, Q0, Q1, Q2, Q3);
        if (dy == 0 || dy == 4) {
            dorow(Q0, Q1, Q2, Q3, C8, C5, C4, false);   // r2 = {8,5,4,5,8}
        } else {
            dorow(Q0, Q1, Q2, Q3, C5, C2, C1, false);   // r2 = {5,2,1,2,5}
        }
    }

    const int ox = tileX0 + lxw;
    const int oy = tileY0 + ty;
    float* drow = &dst[oy * IMG_W + ox];
    float4 o0, o1;
    o0.x = accA.x * FAST_RCP(wsA.x);   // ws >= 1 (center tap), clip(1e-10) is dead
    o0.y = accA.y * FAST_RCP(wsA.y);
    o0.z = accB.x * FAST_RCP(wsB.x);
    o0.w = accB.y * FAST_RCP(wsB.y);
    o1.x = accC.x * FAST_RCP(wsC.x);
    o1.y = accC.y * FAST_RCP(wsC.y);
    o1.z = accD.x * FAST_RCP(wsD.x);
    o1.w = accD.y * FAST_RCP(wsD.y);
    *reinterpret_cast<float4*>(drow) = o0;
    *reinterpret_cast<float4*>(drow + 4) = o1;
}

extern "C" void kernel_launch(void* const* d_in, const int* in_sizes, int n_in,
                              void* d_out, int out_size, void* d_ws, size_t ws_size,
                              hipStream_t stream) {
    const float* x = (const float*)d_in[0];
    // d_in[1] (spatial 5x5) is analytically exp(-(dx^2+dy^2)/8); folded into constants.
    float* out = (float*)d_out;

    const int n_img = out_size / (IMG_H * IMG_W);   // B*C = 24
    dim3 grid(IMG_W / TX, IMG_H / TY, n_img);       // (8, 16, 24)
    dim3 block(256);
    hipLaunchKernelGGL(bilateral_kernel, grid, block, 0, stream, x, out);
}

// Round 4
// 145.132 us; speedup vs baseline: 1.3052x; 1.3052x over previous
//
#include <hip/hip_runtime.h>
#include <stdint.h>

// Bilateral filter denoiser: K=5, sigma_s=2.0, sigma_r=0.1, B=8,C=3,H=512,W=512, fp32.
// weight(dy,dx) = exp(-(n-c)^2/(2*0.1^2)) * exp(-(dx^2+dy^2)/8)
//              = exp2( RC*(n-c)^2 + L[r2] ),  r2 = (dy-2)^2+(dx-2)^2, L[r2] = -r2*log2(e)/8
// arg computed as fma(fma(RC,n,B), n, C0L), B=-2RC*c, C0L=RC*c^2 + L (2 FMAs/tap, spatial
// weight folded into the exponent constant -- 5 distinct L values hoisted per pixel).
//
// 8 px/thread (four float2 halves -> v_pk_* packed fp32), 64x32 tile, 256 threads.
// ALL values are individual v2f locals passed BY VALUE -- round 3's H4 struct passed by
// const& defeated SROA and put coefficients in scratch (+480 MB HBM traffic, 3.6x slower).
// __launch_bounds__(256,3): 170-VGPR cap (measured occupancy was ~3 waves/SIMD anyway);
// the (256,4) 128-cap risks spill at ~118 live VGPRs.
//
// Staging: async global->LDS via __builtin_amdgcn_global_load_lds width=16.
// Tile rows are 72 words (288B = 18x16B units) covering gx in [tileX0-4, tileX0+68):
//   - rows 16B-aligned, LDS written linearly (wave-uniform base + lane*16) as HW requires
//   - per-lane global address handles y-reflect; x is CLAMPED to [0,508] (garbage columns
//     are outside the compute window except 2 cols on x-border blocks, fixed up scalar)
//   - 648 units total = 3 gload_lds instrs/wave (64 + 64 + 34 active lanes)
// Compute window for thread = 16 words [txg*8, txg*8+16): four aligned ds_read_b128
// (Q0..Q3); pixels are words +4..+11 (Q1,Q2), taps use words +2..+13.
// Center tap: weight == 1 exactly -> ws init 1, acc init c; ws>=1 so no clip, rcp ok.

#define KK 5
#define HALO 2
#define TX 64          // tile width (pixels)
#define TY 32          // tile height
#define PXT 8          // pixels per thread along x
#define LW 72          // staged words per row: [tileX0-4, tileX0+68)
#define LH (TY + 2*HALO)   // 36 rows
#define LSTRIDE 72         // 288B rows, 16B-aligned
#define UNITS_PER_ROW 18   // 72 words / 4
#define IMG_H 512
#define IMG_W 512

typedef float v2f __attribute__((ext_vector_type(2)));
typedef float v4f __attribute__((ext_vector_type(4)));

#if defined(__has_builtin)
#if __has_builtin(__builtin_amdgcn_exp2f)
#define FAST_EXP2(x) __builtin_amdgcn_exp2f(x)
#else
#define FAST_EXP2(x) exp2f(x)
#endif
#if __has_builtin(__builtin_amdgcn_rcpf)
#define FAST_RCP(x) __builtin_amdgcn_rcpf(x)
#else
#define FAST_RCP(x) (1.0f / (x))
#endif
#if __has_builtin(__builtin_amdgcn_global_load_lds)
#define HAVE_GLOAD_LDS 1
#endif
#else
#define FAST_EXP2(x) exp2f(x)
#define FAST_RCP(x) (1.0f / (x))
#endif

__device__ __forceinline__ int reflect_idx(int i, int n) {
    i = (i < 0) ? -i : i;
    i = (i >= n) ? (2 * n - 2 - i) : i;
    return i;
}

#ifdef HAVE_GLOAD_LDS
__device__ __forceinline__ void async_copy16(const float* g, float* l) {
    // generic->AS(1) cast for global src; LDS ptr via 32-bit truncation (flat LDS
    // addresses are aperture|offset with 4GB-aligned aperture -> low 32 bits = offset).
    auto gp = (const __attribute__((address_space(1))) void*)g;
    auto lp = (__attribute__((address_space(3))) void*)(uint32_t)(uintptr_t)l;
    __builtin_amdgcn_global_load_lds(gp, lp, 16, 0, 0);
}
#endif

__global__ __launch_bounds__(256, 3)
void bilateral_kernel(const float* __restrict__ x, float* __restrict__ out) {
    __shared__ alignas(16) float tile[LH * LSTRIDE];

    const int tid = threadIdx.x;
    const int tileX0 = blockIdx.x * TX;
    const int tileY0 = blockIdx.y * TY;
    const int img = blockIdx.z;
    const float* __restrict__ src = x + (size_t)img * (IMG_H * IMG_W);
    float* __restrict__ dst = out + (size_t)img * (IMG_H * IMG_W);

#ifdef HAVE_GLOAD_LDS
    // ---- async stage: 648 16B units over 4 waves (162 each = 64 + 64 + 34) ----
    {
        const int wv = tid >> 6;
        const int ln = tid & 63;
        const int u0 = wv * 162;
        #pragma unroll
        for (int k = 0; k < 3; k++) {
            if (k < 2 || ln < 34) {
                int u = u0 + k * 64 + ln;
                int r = u / UNITS_PER_ROW;
                int c = u - r * UNITS_PER_ROW;
                int gy = reflect_idx(tileY0 - HALO + r, IMG_H);
                int gxw = tileX0 - 4 + c * 4;
                gxw = max(gxw, 0); gxw = min(gxw, IMG_W - 4);
                async_copy16(src + gy * IMG_W + gxw, &tile[(u0 + k * 64) * 4]);
            }
        }
    }
    __syncthreads();   // drains vmcnt -> gload_lds data visible

    // ---- x-border fixup: clamped loads put wrong values in 2 needed halo cols ----
    {
        const bool isL = (tileX0 == 0);
        const bool isR = (tileX0 == IMG_W - TX);
        if (isL | isR) {
            if (tid < 2 * LH) {
                int r = tid >> 1, k = tid & 1;
                int gy = reflect_idx(tileY0 - HALO + r, IMG_H);
                const float* srow = src + gy * IMG_W;
                if (isL) tile[r * LSTRIDE + 2 + k] = srow[2 - k];        // gx -2,-1 -> 2,1
                else     tile[r * LSTRIDE + 68 + k] = srow[510 - k];     // gx 512,513 -> 510,509
            }
            __syncthreads();
        }
    }
#else
    // fallback: float2-vectorized manual staging
    for (int u = tid; u < LH * (LW / 2); u += 256) {
        int r = u / (LW / 2);
        int c = (u - r * (LW / 2)) * 2;
        int gy = reflect_idx(tileY0 - HALO + r, IMG_H);
        const float* srow = src + gy * IMG_W;
        int gx0 = tileX0 - 4 + c;
        float2 v;
        if (gx0 >= 0 && gx0 + 1 < IMG_W) {
            v = *reinterpret_cast<const float2*>(&srow[gx0]);
        } else {
            v.x = srow[reflect_idx(gx0, IMG_W)];
            v.y = srow[reflect_idx(gx0 + 1, IMG_W)];
        }
        *reinterpret_cast<float2*>(&tile[r * LSTRIDE + c]) = v;
    }
    __syncthreads();
#endif

    const int txg = tid & 7;       // thread x-group: 0..7
    const int ty  = tid >> 3;      // thread row:     0..31
    const int lxw = txg * PXT;     // first word of this thread's 4-quad read window

    const float RC = -72.13475204444817f;        // -1/(2*0.1^2) * log2(e)
    // L[r2] = -r2 * log2(e)/8, r2 in {1,2,4,5,8}
    const float L1 = -0.18033688011112043f;
    const float L2 = -0.36067376022224086f;
    const float L4 = -0.7213475204444817f;
    const float L5 = -0.9016844005556021f;
    const float L8 = -1.4426950408889634f;
    const v2f RCv = {RC, RC};

    // aligned b128 row reads: 16 words at (ty+dy)*72 + lxw (32B-aligned)
    auto ldrow = [&](int dy, v4f& Q0, v4f& Q1, v4f& Q2, v4f& Q3) {
        const v4f* p = reinterpret_cast<const v4f*>(&tile[(ty + dy) * LSTRIDE + lxw]);
        Q0 = p[0]; Q1 = p[1]; Q2 = p[2]; Q3 = p[3];
    };

    // center row (dy=2): pixels are words +4..+11 = Q1,Q2
    v4f Q20, Q21, Q22, Q23;
    ldrow(2, Q20, Q21, Q22, Q23);
    const v2f cA = {Q21[0], Q21[1]};
    const v2f cB = {Q21[2], Q21[3]};
    const v2f cC = {Q22[0], Q22[1]};
    const v2f cD = {Q22[2], Q22[3]};

    // per-pixel exponent-poly coefficients: arg = RC*n^2 + B*n + (C0 + L[r2])
    const v2f BA = cA * (-2.0f * RC);
    const v2f BB = cB * (-2.0f * RC);
    const v2f BC = cC * (-2.0f * RC);
    const v2f BD = cD * (-2.0f * RC);
    const v2f C0A = (cA * cA) * RC;
    const v2f C0B = (cB * cB) * RC;
    const v2f C0C = (cC * cC) * RC;
    const v2f C0D = (cD * cD) * RC;
    const v2f C1A = C0A + L1, C1B = C0B + L1, C1C = C0C + L1, C1D = C0D + L1;
    const v2f C2A = C0A + L2, C2B = C0B + L2, C2C = C0C + L2, C2D = C0D + L2;
    const v2f C4A = C0A + L4, C4B = C0B + L4, C4C = C0C + L4, C4D = C0D + L4;
    const v2f C5A = C0A + L5, C5B = C0B + L5, C5C = C0C + L5, C5D = C0D + L5;
    const v2f C8A = C0A + L8, C8B = C0B + L8, C8C = C0C + L8, C8D = C0D + L8;

    // center tap folded in: weight exactly 1
    v2f wsA = {1.0f, 1.0f}, wsB = {1.0f, 1.0f}, wsC = {1.0f, 1.0f}, wsD = {1.0f, 1.0f};
    v2f accA = cA, accB = cB, accC = cC, accD = cD;

    auto tap = [&](v2f nA, v2f nB, v2f nC, v2f nD, v2f CA, v2f CB, v2f CC, v2f CD) {
        v2f tA = __builtin_elementwise_fma(__builtin_elementwise_fma(RCv, nA, BA), nA, CA);
        v2f tB = __builtin_elementwise_fma(__builtin_elementwise_fma(RCv, nB, BB), nB, CB);
        v2f tC = __builtin_elementwise_fma(__builtin_elementwise_fma(RCv, nC, BC), nC, CC);
        v2f tD = __builtin_elementwise_fma(__builtin_elementwise_fma(RCv, nD, BD), nD, CD);
        v2f eA, eB, eC, eD;
        eA.x = FAST_EXP2(tA.x); eA.y = FAST_EXP2(tA.y);
        eB.x = FAST_EXP2(tB.x); eB.y = FAST_EXP2(tB.y);
        eC.x = FAST_EXP2(tC.x); eC.y = FAST_EXP2(tC.y);
        eD.x = FAST_EXP2(tD.x); eD.y = FAST_EXP2(tD.y);
        wsA += eA; wsB += eB; wsC += eC; wsD += eD;
        accA = __builtin_elementwise_fma(eA, nA, accA);
        accB = __builtin_elementwise_fma(eB, nB, accB);
        accC = __builtin_elementwise_fma(eC, nC, accC);
        accD = __builtin_elementwise_fma(eD, nD, accD);
    };

    // window words w0..w15 (quads Q0..Q3), taps use w2..w13.
    // even pairs Ek=(w2k,w2k+1) k=1..6; odd pairs Ok=(w2k+1,w2k+2) k=1..5.
    //  dx0:(E1..E4)  dx1:(O1..O4)  dx2:(E2..E5)  dx3:(O2..O5)  dx4:(E3..E6)
    auto dorow = [&](v4f Q0, v4f Q1, v4f Q2, v4f Q3,
                     v2f CaA, v2f CaB, v2f CaC, v2f CaD,
                     v2f CbA, v2f CbB, v2f CbC, v2f CbD,
                     v2f CcA, v2f CcB, v2f CcC, v2f CcD, bool center_row) {
        v2f E1 = {Q0[2], Q0[3]};
        v2f E2 = {Q1[0], Q1[1]};
        v2f E3 = {Q1[2], Q1[3]};
        v2f E4 = {Q2[0], Q2[1]};
        v2f E5 = {Q2[2], Q2[3]};
        v2f E6 = {Q3[0], Q3[1]};
        v2f O1 = {Q0[3], Q1[0]};
        v2f O2 = {Q1[1], Q1[2]};
        v2f O3 = {Q1[3], Q2[0]};
        v2f O4 = {Q2[1], Q2[2]};
        v2f O5 = {Q2[3], Q3[0]};
        tap(E1, E2, E3, E4, CaA, CaB, CaC, CaD);                   // dx = 0
        tap(O1, O2, O3, O4, CbA, CbB, CbC, CbD);                   // dx = 1
        if (!center_row) tap(E2, E3, E4, E5, CcA, CcB, CcC, CcD);  // dx = 2
        tap(O2, O3, O4, O5, CbA, CbB, CbC, CbD);                   // dx = 3
        tap(E3, E4, E5, E6, CaA, CaB, CaC, CaD);                   // dx = 4
    };

    // dy = 2 first (row already loaded): r2 = {4,1,-,1,4}
    dorow(Q20, Q21, Q22, Q23,
          C4A, C4B, C4C, C4D, C1A, C1B, C1C, C1D, C1A, C1B, C1C, C1D, true);

    #pragma unroll
    for (int dy = 0; dy < KK; dy++) {
        if (dy == 2) continue;
        v4f Q0, Q1, Q2, Q3;
        ldrow(dy, Q0, Q1, Q2, Q3);
        if (dy == 0 || dy == 4) {
            // r2 = {8,5,4,5,8}
            dorow(Q0, Q1, Q2, Q3,
                  C8A, C8B, C8C, C8D, C5A, C5B, C5C, C5D, C4A, C4B, C4C, C4D, false);
        } else {
            // r2 = {5,2,1,2,5}
            dorow(Q0, Q1, Q2, Q3,
                  C5A, C5B, C5C, C5D, C2A, C2B, C2C, C2D, C1A, C1B, C1C, C1D, false);
        }
    }

    const int ox = tileX0 + lxw;
    const int oy = tileY0 + ty;
    float* drow = &dst[oy * IMG_W + ox];
    float4 o0, o1;
    o0.x = accA.x * FAST_RCP(wsA.x);   // ws >= 1 (center tap), clip(1e-10) is dead
    o0.y = accA.y * FAST_RCP(wsA.y);
    o0.z = accB.x * FAST_RCP(wsB.x);
    o0.w = accB.y * FAST_RCP(wsB.y);
    o1.x = accC.x * FAST_RCP(wsC.x);
    o1.y = accC.y * FAST_RCP(wsC.y);
    o1.z = accD.x * FAST_RCP(wsD.x);
    o1.w = accD.y * FAST_RCP(wsD.y);
    *reinterpret_cast<float4*>(drow) = o0;
    *reinterpret_cast<float4*>(drow + 4) = o1;
}

extern "C" void kernel_launch(void* const* d_in, const int* in_sizes, int n_in,
                              void* d_out, int out_size, void* d_ws, size_t ws_size,
                              hipStream_t stream) {
    const float* x = (const float*)d_in[0];
    // d_in[1] (spatial 5x5) is analytically exp(-(dx^2+dy^2)/8); folded into constants.
    float* out = (float*)d_out;

    const int n_img = out_size / (IMG_H * IMG_W);   // B*C = 24
    dim3 grid(IMG_W / TX, IMG_H / TY, n_img);       // (8, 16, 24)
    dim3 block(256);
    hipLaunchKernelGGL(bilateral_kernel, grid, block, 0, stream, x, out);
}

// Round 5
// 92.348 us; speedup vs baseline: 2.0513x; 1.5716x over previous
//
#include <hip/hip_runtime.h>
#include <stdint.h>

// Bilateral filter denoiser: K=5, sigma_s=2.0, sigma_r=0.1, B=8,C=3,H=512,W=512, fp32.
// weight(dy,dx) = exp(-(n-c)^2/(2*0.1^2)) * exp(-(dx^2+dy^2)/8)
//              = exp2( RC*(n-c)^2 + L[r2] ),  r2 = (dy-2)^2+(dx-2)^2, L[r2] = -r2*log2(e)/8
// arg computed as fma(fma(RC,n,B), n, C0L), B=-2RC*c, C0L=RC*c^2 + L (2 FMAs/tap, spatial
// weight folded into the exponent constant -- 5 distinct L values hoisted per pixel).
//
// 8 px/thread (four float2 halves -> v_pk_* packed fp32), 64x32 tile, 256 threads.
// ALL compute is expressed via MACROS, not lambdas/functions: rounds 3-4 showed the
// inliner OUTLINES large [&]-capture lambdas at 24 call sites (capture struct in scratch,
// +200 MB HBM scratch traffic, VGPR stuck at 84 while VALUBusy collapsed). Textual
// expansion guarantees inlining and keeps every value in registers.
// __launch_bounds__(256,3): 170-VGPR cap (~118 live expected).
//
// Staging: async global->LDS via __builtin_amdgcn_global_load_lds width=16.
// Tile rows are 72 words (288B = 18x16B units) covering gx in [tileX0-4, tileX0+68):
//   - rows 16B-aligned, LDS written linearly (wave-uniform base + lane*16) as HW requires
//   - per-lane global address handles y-reflect; x is CLAMPED to [0,508] (garbage columns
//     are outside the compute window except 2 cols on x-border blocks, fixed up scalar)
//   - 648 units total = 3 gload_lds instrs/wave (64 + 64 + 34 active lanes)
// Compute window for thread = 16 words [txg*8, txg*8+16): four aligned ds_read_b128
// (Q0..Q3); pixels are words +4..+11 (Q1,Q2), taps use words +2..+13.
// Center tap: weight == 1 exactly -> ws init 1, acc init c; ws>=1 so no clip, rcp ok.

#define KK 5
#define HALO 2
#define TX 64          // tile width (pixels)
#define TY 32          // tile height
#define PXT 8          // pixels per thread along x
#define LW 72          // staged words per row: [tileX0-4, tileX0+68)
#define LH (TY + 2*HALO)   // 36 rows
#define LSTRIDE 72         // 288B rows, 16B-aligned
#define UNITS_PER_ROW 18   // 72 words / 4
#define IMG_H 512
#define IMG_W 512

typedef float v2f __attribute__((ext_vector_type(2)));
typedef float v4f __attribute__((ext_vector_type(4)));

#if defined(__has_builtin)
#if __has_builtin(__builtin_amdgcn_exp2f)
#define FAST_EXP2(x) __builtin_amdgcn_exp2f(x)
#else
#define FAST_EXP2(x) exp2f(x)
#endif
#if __has_builtin(__builtin_amdgcn_rcpf)
#define FAST_RCP(x) __builtin_amdgcn_rcpf(x)
#else
#define FAST_RCP(x) (1.0f / (x))
#endif
#if __has_builtin(__builtin_amdgcn_global_load_lds)
#define HAVE_GLOAD_LDS 1
#endif
#else
#define FAST_EXP2(x) exp2f(x)
#define FAST_RCP(x) (1.0f / (x))
#endif

__device__ __forceinline__ int reflect_idx(int i, int n) {
    i = (i < 0) ? -i : i;
    i = (i >= n) ? (2 * n - 2 - i) : i;
    return i;
}

#ifdef HAVE_GLOAD_LDS
__device__ __forceinline__ void async_copy16(const float* g, float* l) {
    // generic->AS(1) cast for global src; LDS ptr via 32-bit truncation (flat LDS
    // addresses are aperture|offset with 4GB-aligned aperture -> low 32 bits = offset).
    auto gp = (const __attribute__((address_space(1))) void*)g;
    auto lp = (__attribute__((address_space(3))) void*)(uint32_t)(uintptr_t)l;
    __builtin_amdgcn_global_load_lds(gp, lp, 16, 0, 0);
}
#endif

// ---- macro compute kernel core (no function boundaries; see header comment) ----
#define PKFMA(a, b, c) __builtin_elementwise_fma((a), (b), (c))

#define TAP(nA, nB, nC, nD, CA, CB, CC, CD) {                                   \
    v2f tA_ = PKFMA(PKFMA(RCv, (nA), BA), (nA), (CA));                          \
    v2f tB_ = PKFMA(PKFMA(RCv, (nB), BB), (nB), (CB));                          \
    v2f tC_ = PKFMA(PKFMA(RCv, (nC), BC), (nC), (CC));                          \
    v2f tD_ = PKFMA(PKFMA(RCv, (nD), BD), (nD), (CD));                          \
    v2f eA_, eB_, eC_, eD_;                                                     \
    eA_.x = FAST_EXP2(tA_.x); eA_.y = FAST_EXP2(tA_.y);                         \
    eB_.x = FAST_EXP2(tB_.x); eB_.y = FAST_EXP2(tB_.y);                         \
    eC_.x = FAST_EXP2(tC_.x); eC_.y = FAST_EXP2(tC_.y);                         \
    eD_.x = FAST_EXP2(tD_.x); eD_.y = FAST_EXP2(tD_.y);                         \
    wsA += eA_; wsB += eB_; wsC += eC_; wsD += eD_;                             \
    accA = PKFMA(eA_, (nA), accA);                                              \
    accB = PKFMA(eB_, (nB), accB);                                              \
    accC = PKFMA(eC_, (nC), accC);                                              \
    accD = PKFMA(eD_, (nD), accD);                                              \
}

// window words w0..w15 (quads Qa..Qd), taps use w2..w13.
// even pairs Ek=(w2k,w2k+1) k=1..6; odd pairs Ok=(w2k+1,w2k+2) k=1..5.
//  dx0:(E1..E4)  dx1:(O1..O4)  dx2:(E2..E5)  dx3:(O2..O5)  dx4:(E3..E6)
#define DOROW(Qa, Qb, Qc, Qd, CaA,CaB,CaC,CaD, CbA,CbB,CbC,CbD, CcA,CcB,CcC,CcD, CENTER) { \
    v2f E1_ = {Qa[2], Qa[3]};                                                   \
    v2f E2_ = {Qb[0], Qb[1]};                                                   \
    v2f E3_ = {Qb[2], Qb[3]};                                                   \
    v2f E4_ = {Qc[0], Qc[1]};                                                   \
    v2f E5_ = {Qc[2], Qc[3]};                                                   \
    v2f E6_ = {Qd[0], Qd[1]};                                                   \
    v2f O1_ = {Qa[3], Qb[0]};                                                   \
    v2f O2_ = {Qb[1], Qb[2]};                                                   \
    v2f O3_ = {Qb[3], Qc[0]};                                                   \
    v2f O4_ = {Qc[1], Qc[2]};                                                   \
    v2f O5_ = {Qc[3], Qd[0]};                                                   \
    TAP(E1_, E2_, E3_, E4_, CaA, CaB, CaC, CaD);          /* dx = 0 */          \
    TAP(O1_, O2_, O3_, O4_, CbA, CbB, CbC, CbD);          /* dx = 1 */          \
    if (!(CENTER)) TAP(E2_, E3_, E4_, E5_, CcA, CcB, CcC, CcD); /* dx = 2 */    \
    TAP(O2_, O3_, O4_, O5_, CbA, CbB, CbC, CbD);          /* dx = 3 */          \
    TAP(E3_, E4_, E5_, E6_, CaA, CaB, CaC, CaD);          /* dx = 4 */          \
}

#define LDROW(dy, Qa, Qb, Qc, Qd) {                                             \
    const v4f* p_ = reinterpret_cast<const v4f*>(&tile[(ty + (dy)) * LSTRIDE + lxw]); \
    Qa = p_[0]; Qb = p_[1]; Qc = p_[2]; Qd = p_[3];                             \
}

__global__ __launch_bounds__(256, 3)
void bilateral_kernel(const float* __restrict__ x, float* __restrict__ out) {
    __shared__ alignas(16) float tile[LH * LSTRIDE];

    const int tid = threadIdx.x;
    const int tileX0 = blockIdx.x * TX;
    const int tileY0 = blockIdx.y * TY;
    const int img = blockIdx.z;
    const float* __restrict__ src = x + (size_t)img * (IMG_H * IMG_W);
    float* __restrict__ dst = out + (size_t)img * (IMG_H * IMG_W);

#ifdef HAVE_GLOAD_LDS
    // ---- async stage: 648 16B units over 4 waves (162 each = 64 + 64 + 34) ----
    {
        const int wv = tid >> 6;
        const int ln = tid & 63;
        const int u0 = wv * 162;
        #pragma unroll
        for (int k = 0; k < 3; k++) {
            if (k < 2 || ln < 34) {
                int u = u0 + k * 64 + ln;
                int r = u / UNITS_PER_ROW;
                int c = u - r * UNITS_PER_ROW;
                int gy = reflect_idx(tileY0 - HALO + r, IMG_H);
                int gxw = tileX0 - 4 + c * 4;
                gxw = max(gxw, 0); gxw = min(gxw, IMG_W - 4);
                async_copy16(src + gy * IMG_W + gxw, &tile[(u0 + k * 64) * 4]);
            }
        }
    }
    __syncthreads();   // drains vmcnt -> gload_lds data visible

    // ---- x-border fixup: clamped loads put wrong values in 2 needed halo cols ----
    {
        const bool isL = (tileX0 == 0);
        const bool isR = (tileX0 == IMG_W - TX);
        if (isL | isR) {
            if (tid < 2 * LH) {
                int r = tid >> 1, k = tid & 1;
                int gy = reflect_idx(tileY0 - HALO + r, IMG_H);
                const float* srow = src + gy * IMG_W;
                if (isL) tile[r * LSTRIDE + 2 + k] = srow[2 - k];        // gx -2,-1 -> 2,1
                else     tile[r * LSTRIDE + 68 + k] = srow[510 - k];     // gx 512,513 -> 510,509
            }
            __syncthreads();
        }
    }
#else
    // fallback: float2-vectorized manual staging
    for (int u = tid; u < LH * (LW / 2); u += 256) {
        int r = u / (LW / 2);
        int c = (u - r * (LW / 2)) * 2;
        int gy = reflect_idx(tileY0 - HALO + r, IMG_H);
        const float* srow = src + gy * IMG_W;
        int gx0 = tileX0 - 4 + c;
        float2 v;
        if (gx0 >= 0 && gx0 + 1 < IMG_W) {
            v = *reinterpret_cast<const float2*>(&srow[gx0]);
        } else {
            v.x = srow[reflect_idx(gx0, IMG_W)];
            v.y = srow[reflect_idx(gx0 + 1, IMG_W)];
        }
        *reinterpret_cast<float2*>(&tile[r * LSTRIDE + c]) = v;
    }
    __syncthreads();
#endif

    const int txg = tid & 7;       // thread x-group: 0..7
    const int ty  = tid >> 3;      // thread row:     0..31
    const int lxw = txg * PXT;     // first word of this thread's 4-quad read window

    const float RC = -72.13475204444817f;        // -1/(2*0.1^2) * log2(e)
    // L[r2] = -r2 * log2(e)/8, r2 in {1,2,4,5,8}
    const float L1 = -0.18033688011112043f;
    const float L2 = -0.36067376022224086f;
    const float L4 = -0.7213475204444817f;
    const float L5 = -0.9016844005556021f;
    const float L8 = -1.4426950408889634f;
    const v2f RCv = {RC, RC};

    // center row (dy=2): pixels are words +4..+11 = Q1,Q2
    v4f Q20, Q21, Q22, Q23;
    LDROW(2, Q20, Q21, Q22, Q23);
    const v2f cA = {Q21[0], Q21[1]};
    const v2f cB = {Q21[2], Q21[3]};
    const v2f cC = {Q22[0], Q22[1]};
    const v2f cD = {Q22[2], Q22[3]};

    // per-pixel exponent-poly coefficients: arg = RC*n^2 + B*n + (C0 + L[r2])
    const v2f BA = cA * (-2.0f * RC);
    const v2f BB = cB * (-2.0f * RC);
    const v2f BC = cC * (-2.0f * RC);
    const v2f BD = cD * (-2.0f * RC);
    const v2f C0A = (cA * cA) * RC;
    const v2f C0B = (cB * cB) * RC;
    const v2f C0C = (cC * cC) * RC;
    const v2f C0D = (cD * cD) * RC;
    const v2f C1A = C0A + L1, C1B = C0B + L1, C1C = C0C + L1, C1D = C0D + L1;
    const v2f C2A = C0A + L2, C2B = C0B + L2, C2C = C0C + L2, C2D = C0D + L2;
    const v2f C4A = C0A + L4, C4B = C0B + L4, C4C = C0C + L4, C4D = C0D + L4;
    const v2f C5A = C0A + L5, C5B = C0B + L5, C5C = C0C + L5, C5D = C0D + L5;
    const v2f C8A = C0A + L8, C8B = C0B + L8, C8C = C0C + L8, C8D = C0D + L8;

    // center tap folded in: weight exactly 1
    v2f wsA = {1.0f, 1.0f}, wsB = {1.0f, 1.0f}, wsC = {1.0f, 1.0f}, wsD = {1.0f, 1.0f};
    v2f accA = cA, accB = cB, accC = cC, accD = cD;

    // dy = 2 first (row already loaded): r2 = {4,1,-,1,4}
    DOROW(Q20, Q21, Q22, Q23,
          C4A, C4B, C4C, C4D, C1A, C1B, C1C, C1D, C1A, C1B, C1C, C1D, true);

    {   // dy = 0: r2 = {8,5,4,5,8}
        v4f Q0, Q1, Q2, Q3;
        LDROW(0, Q0, Q1, Q2, Q3);
        DOROW(Q0, Q1, Q2, Q3,
              C8A, C8B, C8C, C8D, C5A, C5B, C5C, C5D, C4A, C4B, C4C, C4D, false);
    }
    {   // dy = 1: r2 = {5,2,1,2,5}
        v4f Q0, Q1, Q2, Q3;
        LDROW(1, Q0, Q1, Q2, Q3);
        DOROW(Q0, Q1, Q2, Q3,
              C5A, C5B, C5C, C5D, C2A, C2B, C2C, C2D, C1A, C1B, C1C, C1D, false);
    }
    {   // dy = 3: r2 = {5,2,1,2,5}
        v4f Q0, Q1, Q2, Q3;
        LDROW(3, Q0, Q1, Q2, Q3);
        DOROW(Q0, Q1, Q2, Q3,
              C5A, C5B, C5C, C5D, C2A, C2B, C2C, C2D, C1A, C1B, C1C, C1D, false);
    }
    {   // dy = 4: r2 = {8,5,4,5,8}
        v4f Q0, Q1, Q2, Q3;
        LDROW(4, Q0, Q1, Q2, Q3);
        DOROW(Q0, Q1, Q2, Q3,
              C8A, C8B, C8C, C8D, C5A, C5B, C5C, C5D, C4A, C4B, C4C, C4D, false);
    }

    const int ox = tileX0 + lxw;
    const int oy = tileY0 + ty;
    float* drow = &dst[oy * IMG_W + ox];
    float4 o0, o1;
    o0.x = accA.x * FAST_RCP(wsA.x);   // ws >= 1 (center tap), clip(1e-10) is dead
    o0.y = accA.y * FAST_RCP(wsA.y);
    o0.z = accB.x * FAST_RCP(wsB.x);
    o0.w = accB.y * FAST_RCP(wsB.y);
    o1.x = accC.x * FAST_RCP(wsC.x);
    o1.y = accC.y * FAST_RCP(wsC.y);
    o1.z = accD.x * FAST_RCP(wsD.x);
    o1.w = accD.y * FAST_RCP(wsD.y);
    *reinterpret_cast<float4*>(drow) = o0;
    *reinterpret_cast<float4*>(drow + 4) = o1;
}

extern "C" void kernel_launch(void* const* d_in, const int* in_sizes, int n_in,
                              void* d_out, int out_size, void* d_ws, size_t ws_size,
                              hipStream_t stream) {
    const float* x = (const float*)d_in[0];
    // d_in[1] (spatial 5x5) is analytically exp(-(dx^2+dy^2)/8); folded into constants.
    float* out = (float*)d_out;

    const int n_img = out_size / (IMG_H * IMG_W);   // B*C = 24
    dim3 grid(IMG_W / TX, IMG_H / TY, n_img);       // (8, 16, 24)
    dim3 block(256);
    hipLaunchKernelGGL(bilateral_kernel, grid, block, 0, stream, x, out);
}